// Round 1
// 236.920 us; speedup vs baseline: 1.1232x; 1.1232x over previous
//
#include <hip/hip_runtime.h>
#include <stdint.h>

#define GD    34
#define RS    39          // padded row stride; 39%32=7 -> max 2 lanes/bank for the strip layout (free)
#define NROW  36          // padded rows (1-halo)
#define CBN   (NROW*RS)   // 1404 words per channel buffer
#define NPIX  1156
#define NT    256
#define NB    1024
#define TPR   7           // 5-pixel strips per row (7*5=35 >= 34)
#define TUSED 238         // 34 rows * 7 strips
#define FS    57          // food-halo row stride; 57%32=25, sparse 3-way only (init-only path)
#define SCRN  2960        // floats: >= 51*57+52+1 (conv reads) and >= 1404+1404 (x0buf+premi)

// wave0 scans the 1024-bin LDS histogram, finds the bin containing rank KK,
// writes sel_bin/sel_rem, zeroes the histogram behind itself.
#define SCAN_PASS(KK) do {                                                         \
    if (wid == 0) {                                                                \
      const int base2 = lane << 4;                                                 \
      int c16[16]; int csum = 0;                                                   \
      _Pragma("unroll")                                                            \
      for (int j = 0; j < 16; ++j) { c16[j] = hist[base2+j]; hist[base2+j] = 0; csum += c16[j]; } \
      int inc = csum;                                                              \
      _Pragma("unroll")                                                            \
      for (int off2 = 1; off2 < 64; off2 <<= 1) { int vv = __shfl_up(inc, off2); if (lane >= off2) inc += vv; } \
      const int excl = inc - csum;                                                 \
      if ((KK) >= excl && (KK) < inc) {                                            \
        int rem = (KK) - excl; int cum = 0;                                        \
        _Pragma("unroll")                                                          \
        for (int j = 0; j < 16; ++j) {                                             \
          if (rem >= cum && rem < cum + c16[j]) { sel_bin = base2 + j; sel_rem = rem - cum; } \
          cum += c16[j];                                                           \
        }                                                                          \
      }                                                                            \
    }                                                                              \
  } while (0)

__global__ __launch_bounds__(NT) __attribute__((amdgpu_waves_per_eu(4, 4)))
void ca_kernel(const float* __restrict__ cell_in,   // [B,4,34,34]
               const float* __restrict__ food_in,   // [B,34,34]
               const float* __restrict__ fc1_w,     // [64,12] (wave-uniform scalar reads)
               const float* __restrict__ fc1_b,     // [64]
               const float* __restrict__ fc2_w,     // [4,64]
               const float* __restrict__ fc2_b,     // [4]
               const float* __restrict__ sk_g,      // [19,19]
               const int*   __restrict__ steps_p,
               float* __restrict__ out)             // [cell | food | tpv | lc]
{
  __shared__ float cbuf[3][CBN];     // ch0..2; ch3 == scent (step-invariant), never stored
  __shared__ float scratch[SCRN];    // x0buf[1404] | premi[1404 ints]; food-halo (init) and hist alias it
  __shared__ int   icl[2][4];
  __shared__ int   inzaz[4];
  __shared__ int   sel_bin, sel_rem;
  __shared__ float fsum[4];
  __shared__ int   lcnt[4];

  float* x0buf = scratch;                       // 36x39 halo'd, x_new ch0 (pre-mask/clip)
  int*   premi = (int*)(scratch + 1404);        // 36x39 halo'd premask ints (halo stays 0)
  int*   hist  = (int*)scratch;                 // aliases x0buf: only live inside radix path,
                                                // self-clears to 0 (the stale-safe value)

  const int tid  = threadIdx.x;
  const int b    = blockIdx.x;
  const int lane = tid & 63;
  const int wid  = tid >> 6;
  const int nsteps = steps_p[0];

  const bool tval = (tid < TUSED);
  const int  trow = tval ? (tid / TPR) : 0;
  const int  c0   = tval ? ((tid % TPR) * 5) : 0;
  const int  nval = tval ? ((c0 <= 29) ? 5 : 4) : 0;   // strip 6 covers cols 30..33
  const int  pb0  = tval ? ((trow+1)*RS + c0 + 1) : (RS+1); // padded base (safe interior if idle)
  const int  p0   = trow*GD + c0;                       // flat pixel base

  // ---------------- init ----------------
  for (int idx = tid; idx < 3*CBN; idx += NT) (&cbuf[0][0])[idx] = 0.f;
  for (int idx = tid; idx < SCRN;  idx += NT) scratch[idx] = 0.f;
  __syncthreads();

  float v3k[5], v1k[5], v2k[5];
  int cnt0 = 0;
#pragma unroll
  for (int j = 0; j < 5; ++j) {
    v3k[j] = 0.f; v1k[j] = 0.f; v2k[j] = 0.f;
    if (j < nval) {
      int p = p0 + j;
      const float* gi = cell_in + (size_t)b*4*NPIX + p;
      float v0 = gi[0], v1 = gi[NPIX], v2 = gi[2*NPIX], v3 = gi[3*NPIX];
      cbuf[0][pb0+j] = v0; cbuf[1][pb0+j] = v1; cbuf[2][pb0+j] = v2;
      v3k[j] = v3;
      cnt0 += (v0 > 0.8f) ? 1 : 0;
      scratch[(trow+9)*FS + (c0+j+9)] = food_in[(size_t)b*NPIX + p];  // 9-halo, stride FS
    }
  }
#pragma unroll
  for (int off = 32; off; off >>= 1) cnt0 += __shfl_down(cnt0, off);
  if (lane == 0) icl[0][wid] = cnt0;
  __syncthreads();

  // scent: 19x19 gaussian conv, once. Row-register reuse: 23 loads/row feed all 5 pixels
  // (accumulation order per pixel is identical to the naive dr-outer/dc-inner loop -> bit-exact).
  float scent[5] = {0.f, 0.f, 0.f, 0.f, 0.f};
  for (int dr = 0; dr < 19; ++dr) {
    const float* frow = scratch + (trow+dr)*FS + c0;
    float f[23];
#pragma unroll
    for (int q = 0; q < 23; ++q) f[q] = frow[q];
    const float* krow = sk_g + dr*19;
#pragma unroll
    for (int dc = 0; dc < 19; ++dc) {
      const float kv = krow[dc];
      scent[0] = fmaf(f[dc+0], kv, scent[0]);
      scent[1] = fmaf(f[dc+1], kv, scent[1]);
      scent[2] = fmaf(f[dc+2], kv, scent[2]);
      scent[3] = fmaf(f[dc+3], kv, scent[3]);
      scent[4] = fmaf(f[dc+4], kv, scent[4]);
    }
  }
  __syncthreads();
  for (int idx = tid; idx < SCRN; idx += NT) scratch[idx] = 0.f;  // premi halo must be 0
  __syncthreads();
#pragma unroll
  for (int j = 0; j < 5; ++j) if (j < nval) x0buf[pb0+j] = scent[j];
  __syncthreads();
  // ch3 := scent every step -> its sobels are step-invariant
  float sxs[5], sys[5];
#pragma unroll
  for (int j = 0; j < 5; ++j) {
    const int bb = (j < nval) ? (pb0 + j) : pb0;
    float t00=x0buf[bb-RS-1], t01=x0buf[bb-RS], t02=x0buf[bb-RS+1];
    float t10=x0buf[bb-1],                      t12=x0buf[bb+1];
    float t20=x0buf[bb+RS-1], t21=x0buf[bb+RS], t22=x0buf[bb+RS+1];
    sxs[j] = ((t02 - t00) + 2.f*(t12 - t10) + (t22 - t20)) * 0.125f;
    sys[j] = ((t20 - t00) + 2.f*(t21 - t01) + (t22 - t02)) * 0.125f;
  }
  // x0buf content is stale-safe (only premask-false pixels ever read stale entries)

  const float b2r0 = fc2_b[0], b2r1 = fc2_b[1], b2r2 = fc2_b[2], b2r3 = fc2_b[3];

  // ---------------- steps ----------------
  for (int s = 0; s < nsteps; ++s) {
    __syncthreads();                       // syncW: prev writeback -> B1 reads
    // --- B1: premask = maxpool3(ch0) > 0.1, rolling 7-col window.
    //     cbuf[0] is immutable until writeback -> cache the 3x7 window in registers
    //     so B2's ch0 stencil needs no LDS reads.
    float r0[7], r1[7], r2[7], cm[7];
#pragma unroll
    for (int jc = 0; jc < 7; ++jc) {
      r0[jc] = 0.f; r1[jc] = 0.f; r2[jc] = 0.f; cm[jc] = 0.f;
      if (jc < nval + 2) {
        const int a = pb0 - 1 + jc;
        r0[jc] = cbuf[0][a-RS]; r1[jc] = cbuf[0][a]; r2[jc] = cbuf[0][a+RS];
        cm[jc] = fmaxf(fmaxf(r0[jc], r1[jc]), r2[jc]);
      }
    }
    unsigned pm = 0;
#pragma unroll
    for (int j = 0; j < 5; ++j) {
      if (j < nval) {
        bool t = fmaxf(fmaxf(cm[j], cm[j+1]), cm[j+2]) > 0.1f;
        premi[pb0+j] = t ? 1 : 0;
        if (t) pm |= (1u << j);
      }
    }
    __syncthreads();                       // syncB
    // --- B2: per-pixel dilated activity (rolling OR) + gated per-pixel MLP ---
    int co[7];
#pragma unroll
    for (int jc = 0; jc < 7; ++jc) {
      co[jc] = 0;
      if (jc < nval + 2) {
        const int a = pb0 - 1 + jc;
        co[jc] = premi[a-RS] | premi[a] | premi[a+RS];
      }
    }
#pragma unroll
    for (int j = 0; j < 5; ++j) {
      int acti = (j < nval) ? (co[j] | co[j+1] | co[j+2]) : 0;
      if (__any(acti)) {
        const int bb = pb0 + j;
        float y0,y1,y2,y4,y5,y6,y8,y9,y10;
        {
          // ch0 from the register window (rows trow..trow+2, cols c0+j..c0+j+2)
          y0 = r1[j+1];
          y4 = ((r0[j+2] - r0[j]) + 2.f*(r1[j+2] - r1[j]) + (r2[j+2] - r2[j])) * 0.125f;
          y8 = ((r2[j] - r0[j]) + 2.f*(r2[j+1] - r0[j+1]) + (r2[j+2] - r0[j+2])) * 0.125f;
        }
        {
          const float* cb = cbuf[1];
          float t00=cb[bb-RS-1], t01=cb[bb-RS], t02=cb[bb-RS+1];
          float t10=cb[bb-1],    t11=cb[bb],    t12=cb[bb+1];
          float t20=cb[bb+RS-1], t21=cb[bb+RS], t22=cb[bb+RS+1];
          y1 = t11;
          y5 = ((t02 - t00) + 2.f*(t12 - t10) + (t22 - t20)) * 0.125f;
          y9 = ((t20 - t00) + 2.f*(t21 - t01) + (t22 - t02)) * 0.125f;
        }
        {
          const float* cb = cbuf[2];
          float t00=cb[bb-RS-1], t01=cb[bb-RS], t02=cb[bb-RS+1];
          float t10=cb[bb-1],    t11=cb[bb],    t12=cb[bb+1];
          float t20=cb[bb+RS-1], t21=cb[bb+RS], t22=cb[bb+RS+1];
          y2 = t11;
          y6 = ((t02 - t00) + 2.f*(t12 - t10) + (t22 - t20)) * 0.125f;
          y10= ((t20 - t00) + 2.f*(t21 - t01) + (t22 - t02)) * 0.125f;
        }
        const float y3 = scent[j], y7 = sxs[j], y11 = sys[j];
        float u0 = b2r0, u1 = b2r1, u2 = b2r2, u3 = b2r3;
        for (int o = 0; o < 64; ++o) {     // weights: wave-uniform scalar loads (K$)
          const float* wr = fc1_w + o*12;
          float t = fc1_b[o];
          t = fmaf(y0, wr[0], t);  t = fmaf(y1, wr[1], t);
          t = fmaf(y2, wr[2], t);  t = fmaf(y3, wr[3], t);
          t = fmaf(y4, wr[4], t);  t = fmaf(y5, wr[5], t);
          t = fmaf(y6, wr[6], t);  t = fmaf(y7, wr[7], t);
          t = fmaf(y8, wr[8], t);  t = fmaf(y9, wr[9], t);
          t = fmaf(y10, wr[10], t); t = fmaf(y11, wr[11], t);
          t = fmaxf(t, 0.f);
          u0 = fmaf(t, fc2_w[o],     u0);
          u1 = fmaf(t, fc2_w[64+o],  u1);
          u2 = fmaf(t, fc2_w[128+o], u2);
          u3 = fmaf(t, fc2_w[192+o], u3);
        }
        v3k[j] = y3 + u3;                  // x_new ch3, pre-clip, held in-place
        if (j < nval) {
          x0buf[bb]  = y0 + u0;            // x_new ch0, pre-mask/clip (for postmask pool)
          v1k[j]     = y1 + u1;            // x_new ch1/ch2 stay in registers (same thread
          v2k[j]     = y2 + u2;            //  writes in B2 and reads in C)
        }
      }
    }
    __syncthreads();                       // sync2
    // --- C: postmask (only where premask), masks+clips, counts ---
    unsigned pq = 0;
    float midv[5];
#pragma unroll
    for (int j = 0; j < 5; ++j) midv[j] = 0.f;
    if (pm) {
      float dm[7];
#pragma unroll
      for (int jc = 0; jc < 7; ++jc) {
        dm[jc] = 0.f;
        if (jc < nval + 2) {
          const int a = pb0 - 1 + jc;
          float u = x0buf[a-RS], m = x0buf[a], d = x0buf[a+RS];
          dm[jc] = fmaxf(fmaxf(u, m), d);
          if (jc >= 1 && jc <= 5) midv[jc-1] = m;   // own x_new ch0 values
        }
      }
#pragma unroll
      for (int j = 0; j < 5; ++j)
        if (fmaxf(fmaxf(dm[j], dm[j+1]), dm[j+2]) > 0.1f) pq |= (1u << j);
    }
    int packed = 0;                        // nz | az<<16
    float v0s[5];
#pragma unroll
    for (int j = 0; j < 5; ++j) {
      v0s[j] = 0.f;
      if (j < nval) {
        bool alive = ((pm >> j) & 1u) && ((pq >> j) & 1u);
        float v0 = 0.f, v1 = 0.f, v2 = 0.f, v3 = 0.f;
        if (alive) {
          v0 = fminf(fmaxf(midv[j],   0.f),  1.f);
          v1 = fminf(fmaxf(v1k[j],  -10.f), 10.f);
          v2 = fminf(fmaxf(v2k[j],  -10.f), 10.f);
          v3 = fminf(fmaxf(v3k[j],  -10.f), 10.f);
        }
        cbuf[1][pb0+j] = v1; cbuf[2][pb0+j] = v2; v3k[j] = v3;
        v0s[j] = v0;
        int zer = (v0 == 0.f) ? 1 : 0;
        int azf = (zer && v1 == 0.f && v2 == 0.f && v3 == 0.f) ? 1 : 0;
        packed += zer + (azf << 16);
      }
    }
#pragma unroll
    for (int off = 32; off; off >>= 1) packed += __shfl_down(packed, off);
    if (lane == 0) inzaz[wid] = packed;
    __syncthreads();                       // sync3 (x0buf fully consumed after this)
    const int t01 = inzaz[0]+inzaz[1]+inzaz[2]+inzaz[3];
    const int nz = t01 & 0xffff, az = t01 >> 16;
    const int cl = icl[s&1][0]+icl[s&1][1]+icl[s&1][2]+icl[s&1][3];
    const int k  = (cl < NPIX) ? cl : (NPIX-1);
    float kth = 0.f;
    if (k >= nz) {                         // rare: k-th value nonzero -> 3-pass radix select
      hist[tid] = 0; hist[tid+256] = 0; hist[tid+512] = 0; hist[tid+768] = 0;  // hist aliases x0buf
      __syncthreads();
      const int k2 = k - nz;
#pragma unroll
      for (int j = 0; j < 5; ++j) {
        unsigned u = __float_as_uint(v0s[j]);
        if (j < nval && u != 0u) atomicAdd(&hist[u >> 20], 1);
      }
      __syncthreads();
      SCAN_PASS(k2);
      __syncthreads();
      const int bin1 = sel_bin; const int kr2 = sel_rem;
#pragma unroll
      for (int j = 0; j < 5; ++j) {
        unsigned u = __float_as_uint(v0s[j]);
        if (j < nval && u != 0u && (u >> 20) == (unsigned)bin1)
          atomicAdd(&hist[(u >> 10) & 1023u], 1);
      }
      __syncthreads();
      SCAN_PASS(kr2);
      __syncthreads();
      const int bin2 = sel_bin; const int kr3 = sel_rem;
      const unsigned pref2 = (((unsigned)bin1) << 10) | (unsigned)bin2;
#pragma unroll
      for (int j = 0; j < 5; ++j) {
        unsigned u = __float_as_uint(v0s[j]);
        if (j < nval && u != 0u && (u >> 10) == pref2)
          atomicAdd(&hist[u & 1023u], 1);
      }
      __syncthreads();
      SCAN_PASS(kr3);
      __syncthreads();
      kth = __uint_as_float((((unsigned)bin1) << 20) | (((unsigned)bin2) << 10) | (unsigned)sel_bin);
      // SCAN_PASS self-clears hist -> x0buf region left zeroed (stale-safe); premi untouched
    }
    // --- writeback + next step's living count ---
    int cnt = 0;
#pragma unroll
    for (int j = 0; j < 5; ++j) {
      if (j < nval) {
        float w0 = (v0s[j] > kth) ? v0s[j] : 0.f;
        cbuf[0][pb0+j] = w0;
        cnt += (w0 > 0.8f) ? 1 : 0;
      }
    }
#pragma unroll
    for (int off = 32; off; off >>= 1) cnt += __shfl_down(cnt, off);
    if (lane == 0) icl[(s+1)&1][wid] = cnt;
    if (az == NPIX) break;                 // all-zero state is an exact fixed point
  }

  // ---------------- epilogue ----------------
  const size_t CELL_N = (size_t)4*NPIX*NB;
  const size_t FOOD_N = (size_t)NPIX*NB;
  float tp = 0.f; int lcv = 0;
#pragma unroll
  for (int j = 0; j < 5; ++j) {
    if (j < nval) {
      const int p = p0 + j;
      float c0v = cbuf[0][pb0+j], c1 = cbuf[1][pb0+j], c2 = cbuf[2][pb0+j]; // self-written
      size_t go = (size_t)b*4*NPIX + p;
      out[go]          = c0v;
      out[go +   NPIX] = c1;
      out[go + 2*NPIX] = c2;
      out[go + 3*NPIX] = v3k[j];
      out[CELL_N + (size_t)b*NPIX + p] = food_in[(size_t)b*NPIX + p];
      tp += c0v;
      lcv += (c0v > 0.1f) ? 1 : 0;
    }
  }
#pragma unroll
  for (int off = 32; off; off >>= 1) { tp += __shfl_down(tp, off); lcv += __shfl_down(lcv, off); }
  if (lane == 0) { fsum[wid] = tp; lcnt[wid] = lcv; }
  __syncthreads();
  if (tid == 0) {
    out[CELL_N + FOOD_N + b]      = fsum[0]+fsum[1]+fsum[2]+fsum[3];
    out[CELL_N + FOOD_N + NB + b] = (float)(lcnt[0]+lcnt[1]+lcnt[2]+lcnt[3]);
  }
}

extern "C" void kernel_launch(void* const* d_in, const int* in_sizes, int n_in,
                              void* d_out, int out_size, void* d_ws, size_t ws_size,
                              hipStream_t stream) {
  const float* cell  = (const float*)d_in[0];
  const float* food  = (const float*)d_in[1];
  const float* fc1w  = (const float*)d_in[2];
  const float* fc1b  = (const float*)d_in[3];
  const float* fc2w  = (const float*)d_in[4];
  const float* fc2b  = (const float*)d_in[5];
  const float* sk    = (const float*)d_in[6];
  const int*   steps = (const int*)d_in[7];
  float* out = (float*)d_out;
  ca_kernel<<<NB, NT, 0, stream>>>(cell, food, fc1w, fc1b, fc2w, fc2b, sk, steps, out);
}